// Round 10
// baseline (91.258 us; speedup 1.0000x reference)
//
#include <hip/hip_runtime.h>

#define K   16          // tracked labels 1..16 (label 0 = background, never in loss)
#define NB  16          // batch
#define NP  409600      // 640*640 pixels per image
#define NPV (NP / 4)    // float4 vectors per image
#define BX  128         // blocks per image -> 2048 blocks
#define NBLK (NB * BX)
#define SIGMA_DIS 3.0f

// ws layout (floats): [0 .. NB*K)        ss table   (atomic-accumulated)
//                     [NB*K .. 2*NB*K)   cnt table
//                     [2*NB*K]           ticket counter (uint)
// All zeroed by a 2KB memset node each call.
//
// Fused: seg-reduce -> 2KB atomic table -> last block (ticket) finalizes.
// No per-block __threadfence (R3 lesson: 1024 device fences = L2 writeback
// storm). Ordering: __syncthreads drains vmcnt after the table atomics
// (atomic complete == visible at coherent point); ticket via scoped
// fetch_add; winner reads the table with agent-scope atomic loads.
__global__ __launch_bounds__(256) void disc_loss_kernel(
    const float* __restrict__ pred,   // (NB, 4, NP)
    const int*   __restrict__ lab,    // (NB, NP)
    float* __restrict__ ws,
    float* __restrict__ out)
{
    const int tid  = threadIdx.x;
    const int lane = tid & 63;
    const int wave = tid >> 6;
    const int b    = blockIdx.y;
    const int bx   = blockIdx.x;

    float* ss_tab  = ws;
    float* cnt_tab = ws + NB * K;
    unsigned int* counter = (unsigned int*)(ws + 2 * NB * K);

    float ssb[K];
    int   cnt[K];
#pragma unroll
    for (int k = 0; k < K; ++k) { ssb[k] = 0.0f; cnt[k] = 0; }

    const float4* p0 = (const float4*)(pred + ((size_t)b * 4 + 0) * NP);
    const float4* p1 = (const float4*)(pred + ((size_t)b * 4 + 1) * NP);
    const float4* p2 = (const float4*)(pred + ((size_t)b * 4 + 2) * NP);
    const float4* p3 = (const float4*)(pred + ((size_t)b * 4 + 3) * NP);
    const int4*   lb = (const int4*)(lab + (size_t)b * NP);

    // bx*256, stride, NPV multiples of 256 -> guard is block-uniform, waves complete.
    for (int v = bx * 256 + tid; v < NPV; v += BX * 256) {
        float4 a = p0[v];
        float4 c = p1[v];
        float4 d = p2[v];
        float4 e = p3[v];
        int4   l = lb[v];

        float s0 = a.x * a.x + c.x * c.x + d.x * d.x + e.x * e.x;
        float s1 = a.y * a.y + c.y * c.y + d.y * d.y + e.y * e.y;
        float s2 = a.z * a.z + c.z * c.z + d.z * d.z + e.z * e.z;
        float s3 = a.w * a.w + c.w * c.w + d.w * d.w + e.w * e.w;

#pragma unroll
        for (int k = 0; k < K; ++k) {
            const int kk = k + 1;
            bool e0 = (l.x == kk);
            bool e1 = (l.y == kk);
            bool e2 = (l.z == kk);
            bool e3 = (l.w == kk);
            ssb[k] += e0 ? s0 : 0.0f;
            ssb[k] += e1 ? s1 : 0.0f;
            ssb[k] += e2 ? s2 : 0.0f;
            ssb[k] += e3 ? s3 : 0.0f;
            // wave-uniform counts on the scalar pipe (vcc -> s_bcnt1 -> s_add)
            cnt[k] += __popcll(__ballot(e0)) + __popcll(__ballot(e1))
                    + __popcll(__ballot(e2)) + __popcll(__ballot(e3));
        }
    }

    // --- wave reduce ss via register butterfly (cnt already wave-uniform) ---
#pragma unroll
    for (int k = 0; k < K; ++k) {
#pragma unroll
        for (int m = 1; m < 64; m <<= 1)
            ssb[k] += __shfl_xor(ssb[k], m, 64);
    }

    __shared__ float ss_sh[4][K];
    __shared__ int   cnt_sh[4][K];
    if (lane == 0) {
#pragma unroll
        for (int k = 0; k < K; ++k) { ss_sh[wave][k] = ssb[k]; cnt_sh[wave][k] = cnt[k]; }
    }
    __syncthreads();

    if (tid < K) {
        float s = ss_sh[0][tid] + ss_sh[1][tid] + ss_sh[2][tid] + ss_sh[3][tid];
        float c = (float)(cnt_sh[0][tid] + cnt_sh[1][tid] + cnt_sh[2][tid] + cnt_sh[3][tid]);
        unsafeAtomicAdd(&ss_tab [b * K + tid], s);
        unsafeAtomicAdd(&cnt_tab[b * K + tid], c);
    }

    // __syncthreads drains each wave's vmcnt -> this block's atomics are
    // complete (visible at the coherent point) before the ticket.
    __syncthreads();

    __shared__ int is_last;
    if (tid == 0) {
        unsigned int old = __hip_atomic_fetch_add(counter, 1u,
                              __ATOMIC_ACQ_REL, __HIP_MEMORY_SCOPE_AGENT);
        is_last = (old == NBLK - 1) ? 1 : 0;
    }
    __syncthreads();
    if (!is_last) return;

    // ---------------- inline finalize (last block only) ----------------
    __shared__ float m_sh[NB][K];
    __shared__ float c_sh[NB][K];
    __shared__ float inv_denom[NB];
    __shared__ float red[256];

    {   // one (b,k) per thread; agent-scope loads bypass stale local caches
        float cc = __hip_atomic_load(&cnt_tab[tid], __ATOMIC_RELAXED,
                                     __HIP_MEMORY_SCOPE_AGENT);
        float ss = __hip_atomic_load(&ss_tab[tid], __ATOMIC_RELAXED,
                                     __HIP_MEMORY_SCOPE_AGENT);
        const int fb = tid >> 4;
        const int fk = tid & 15;
        c_sh[fb][fk] = cc;
        m_sh[fb][fk] = (cc > 0.0f) ? ss / (cc * cc) : 0.0f;
    }
    __syncthreads();

    if (tid < NB) {
        int nk = 0;                               // max label value present (bins = labels 1..16)
        for (int k = K; k >= 1; --k) {
            if (c_sh[tid][k - 1] > 0.0f) { nk = k; break; }
        }
        float denom = (float)(nk * (nk - 1));
        inv_denom[tid] = (nk > 1) ? 1.0f / fmaxf(denom, 1.0f) : 0.0f;
    }
    __syncthreads();

    float acc = 0.0f;
    for (int e = tid; e < NB * K * K; e += 256) { // 4096 items, 16 iters
        const int fb = e >> 8;
        const int ij = e & 255;
        const int ki = ij >> 4;                   // label ki+1
        const int kj = ij & 15;                   // label kj+1
        if (kj > ki && c_sh[fb][ki] > 0.0f && c_sh[fb][kj] > 0.0f) {
            float s2 = m_sh[fb][ki] + m_sh[fb][kj];
            float dd = sqrtf(s2);
            float x  = SIGMA_DIS - dd;
            acc += log1pf(x * x) * inv_denom[fb];
        }
    }

    red[tid] = acc;
    __syncthreads();
    for (int s = 128; s > 0; s >>= 1) {
        if (tid < s) red[tid] += red[tid + s];
        __syncthreads();
    }
    if (tid == 0) out[0] = red[0];
}

extern "C" void kernel_launch(void* const* d_in, const int* in_sizes, int n_in,
                              void* d_out, int out_size, void* d_ws, size_t ws_size,
                              hipStream_t stream) {
    const float* pred = (const float*)d_in[0];
    const int*   lab  = (const int*)d_in[1];
    float* out = (float*)d_out;

    // zero ss table + cnt table + ticket counter (2052 B, round up)
    hipMemsetAsync(d_ws, 0, (2 * NB * K + 16) * sizeof(float), stream);

    dim3 grid(BX, NB);
    disc_loss_kernel<<<grid, 256, 0, stream>>>(pred, lab, (float*)d_ws, out);
}